// Round 9
// baseline (17.372 us; speedup 1.0000x reference)
//
#include <hip/hip_runtime.h>

#define N_SP 2304      // H*W = 48*48
#define C_CH 256
#define B_B  8
#define NTILE 256              // n-positions per K1 block (64 lanes x float4)
#define TILES 9                // N_SP / NTILE
#define NBLK1 (B_B * TILES)    // 72
#define BN_EPS 1e-5f

// workspace layout (float offsets)
#define WS_THETA 0                 // 8*2304 = 18432 floats
#define WS_PG    18432             // 72
#define WS_TH    (18432 + 72)      // 72
#define WS_TH2   (18432 + 144)     // 72

// K1: per-(b, 256-n tile) projections, float4 loads (1KiB/wave-instruction).
// 8 waves each own a 32-channel chunk; float4 accumulators; LDS cross-wave
// reduce; wave 0 finishes (theta float4 store + partial sums).
__global__ __launch_bounds__(512) void proj_kernel(
    const float* __restrict__ x,
    const float* __restrict__ gw, const float* __restrict__ gb,
    const float* __restrict__ tw, const float* __restrict__ tb,
    const float* __restrict__ pw, const float* __restrict__ pb,
    float* __restrict__ ws)
{
    __shared__ float4 pt[8][64], pp[8][64], pgv[8][64];   // 24 KiB

    const int tid  = threadIdx.x;
    const int w    = tid >> 6;
    const int lane = tid & 63;
    const int blk  = blockIdx.x;
    const int b    = blk / TILES;
    const int tile = blk - b * TILES;

    const int cbase = __builtin_amdgcn_readfirstlane(w * 32);   // SGPR
    // base of this thread's float4 within the tile
    const float* xp = x + (size_t)(b * C_CH + cbase) * N_SP + tile * NTILE + lane * 4;

    float4 at = {0.f, 0.f, 0.f, 0.f};
    float4 ap = {0.f, 0.f, 0.f, 0.f};
    float4 ag = {0.f, 0.f, 0.f, 0.f};
    #pragma unroll
    for (int c = 0; c < 32; ++c) {
        const float4 v = *(const float4*)(xp + (size_t)c * N_SP);  // 1KiB/wave
        const float wt = tw[cbase + c];           // s_load (scalar cache)
        const float wp = pw[cbase + c];
        const float wg = gw[cbase + c];
        at.x = fmaf(wt, v.x, at.x); at.y = fmaf(wt, v.y, at.y);
        at.z = fmaf(wt, v.z, at.z); at.w = fmaf(wt, v.w, at.w);
        ap.x = fmaf(wp, v.x, ap.x); ap.y = fmaf(wp, v.y, ap.y);
        ap.z = fmaf(wp, v.z, ap.z); ap.w = fmaf(wp, v.w, ap.w);
        ag.x = fmaf(wg, v.x, ag.x); ag.y = fmaf(wg, v.y, ag.y);
        ag.z = fmaf(wg, v.z, ag.z); ag.w = fmaf(wg, v.w, ag.w);
    }
    pt[w][lane]  = at;
    pp[w][lane]  = ap;
    pgv[w][lane] = ag;
    __syncthreads();

    if (tid < 64) {
        float4 st = {0.f,0.f,0.f,0.f}, sp = {0.f,0.f,0.f,0.f}, sg = {0.f,0.f,0.f,0.f};
        #pragma unroll
        for (int j = 0; j < 8; ++j) {
            const float4 a = pt[j][tid], p = pp[j][tid], g = pgv[j][tid];
            st.x += a.x; st.y += a.y; st.z += a.z; st.w += a.w;
            sp.x += p.x; sp.y += p.y; sp.z += p.z; sp.w += p.w;
            sg.x += g.x; sg.y += g.y; sg.z += g.z; sg.w += g.w;
        }
        const float tbv = tb[0], pbv = pb[0], gbv = gb[0];
        float4 th, ph, gg;
        th.x = st.x + tbv; th.y = st.y + tbv; th.z = st.z + tbv; th.w = st.w + tbv;
        ph.x = sp.x + pbv; ph.y = sp.y + pbv; ph.z = sp.z + pbv; ph.w = sp.w + pbv;
        gg.x = sg.x + gbv; gg.y = sg.y + gbv; gg.z = sg.z + gbv; gg.w = sg.w + gbv;

        *(float4*)(ws + WS_THETA + b * N_SP + tile * NTILE + tid * 4) = th;

        float r_pg  = ph.x*gg.x + ph.y*gg.y + ph.z*gg.z + ph.w*gg.w;
        float r_th  = th.x + th.y + th.z + th.w;
        float r_th2 = th.x*th.x + th.y*th.y + th.z*th.z + th.w*th.w;
        #pragma unroll
        for (int off = 32; off >= 1; off >>= 1) {
            r_pg  += __shfl_xor(r_pg,  off, 64);
            r_th  += __shfl_xor(r_th,  off, 64);
            r_th2 += __shfl_xor(r_th2, off, 64);
        }
        if (tid == 0) {
            ws[WS_PG  + blk] = r_pg;
            ws[WS_TH  + blk] = r_th;
            ws[WS_TH2 + blk] = r_th2;
        }
    }
}

// K3: 256 blocks x 512 threads. One finalize prologue per block (wave 0),
// then each WAVE streams one full (b,c) row (wave-uniform c -> s_loads).
// (structure identical to R7; only the partial-reduce geometry changed)
__global__ __launch_bounds__(512) void out_kernel(
    const float* __restrict__ x,  const float* __restrict__ ww,
    const float* __restrict__ gamma, const float* __restrict__ beta,
    const float* __restrict__ ws, float* __restrict__ out)
{
    __shared__ float fS[B_B], fTH[B_B], fTH2[B_B];
    const int tid = threadIdx.x;

    // ---- finalize prologue: wave 0 reduces the 3x72 partials ----
    if (tid < 64) {
        const int fb = tid >> 3;        // 8 groups of 8 lanes
        const int l  = tid & 7;
        float pg = 0.f, th = 0.f, th2 = 0.f;
        #pragma unroll
        for (int k = 0; k < 2; ++k) {
            const int t = l + 8 * k;
            if (t < TILES) {
                pg  += ws[WS_PG  + fb * TILES + t];
                th  += ws[WS_TH  + fb * TILES + t];
                th2 += ws[WS_TH2 + fb * TILES + t];
            }
        }
        #pragma unroll
        for (int off = 4; off >= 1; off >>= 1) {
            pg  += __shfl_xor(pg,  off, 64);
            th  += __shfl_xor(th,  off, 64);
            th2 += __shfl_xor(th2, off, 64);
        }
        if (l == 0) {
            fS[fb]   = pg / (float)N_SP;   // s_b
            fTH[fb]  = th;
            fTH2[fb] = th2;
        }
    }
    __syncthreads();

    const int blk  = blockIdx.x;                       // 0..255
    const int b    = blk >> 5;                          // 32 blocks per b
    const int c0   = (blk & 31) * 8;                    // 8 channels per block
    const int w    = __builtin_amdgcn_readfirstlane(tid >> 6);  // wave id
    const int lane = tid & 63;
    const int c    = c0 + w;                            // wave-uniform channel

    float ybar = 0.f, ey2 = 0.f;
    #pragma unroll
    for (int bb = 0; bb < B_B; ++bb) {
        ybar += fS[bb] * fTH[bb];     // LDS broadcast reads
        ey2  += fS[bb] * fS[bb] * fTH2[bb];
    }
    const float inv = 1.0f / (float)(B_B * N_SP);
    ybar *= inv;
    ey2  *= inv;
    const float vary = ey2 - ybar * ybar;

    const float wv = ww[c];          // wave-uniform -> s_load
    const float sc = gamma[c] * wv * rsqrtf(fmaf(wv * wv, vary, BN_EPS));
    const float s  = fS[b];
    const float be = beta[c];
    const float yb = ybar;

    const size_t row = ((size_t)b * C_CH + c) * N_SP;
    const float4* xr   = (const float4*)(x + row);
    const float4* tr   = (const float4*)(ws + WS_THETA + b * N_SP);
    float4*       orow = (float4*)((float*)out + row);

    #pragma unroll
    for (int k = 0; k < 9; ++k) {
        const int i = lane + k * 64;   // 9*64*4 = 2304 floats exactly
        float4 xv = xr[i];
        float4 tv = tr[i];
        float4 o;
        o.x = fmaf(sc, fmaf(tv.x, s, -yb), xv.x + be);
        o.y = fmaf(sc, fmaf(tv.y, s, -yb), xv.y + be);
        o.z = fmaf(sc, fmaf(tv.z, s, -yb), xv.z + be);
        o.w = fmaf(sc, fmaf(tv.w, s, -yb), xv.w + be);
        orow[i] = o;
    }
}

extern "C" void kernel_launch(void* const* d_in, const int* in_sizes, int n_in,
                              void* d_out, int out_size, void* d_ws, size_t ws_size,
                              hipStream_t stream) {
    const float* x        = (const float*)d_in[0];
    const float* g_w      = (const float*)d_in[1];
    const float* g_b      = (const float*)d_in[2];
    const float* theta_w  = (const float*)d_in[3];
    const float* theta_b  = (const float*)d_in[4];
    const float* phi_w    = (const float*)d_in[5];
    const float* phi_b    = (const float*)d_in[6];
    const float* w_w      = (const float*)d_in[7];
    // d_in[8] = w_b : cancels in training-mode BatchNorm (mean subtraction)
    const float* bn_gamma = (const float*)d_in[9];
    const float* bn_beta  = (const float*)d_in[10];

    float* ws  = (float*)d_ws;
    float* out = (float*)d_out;

    proj_kernel<<<NBLK1, 512, 0, stream>>>(x, g_w, g_b, theta_w, theta_b,
                                           phi_w, phi_b, ws);
    out_kernel<<<256, 512, 0, stream>>>(x, w_w, bn_gamma, bn_beta, ws, out);
}